// Round 11
// baseline (107.541 us; speedup 1.0000x reference)
//
#include <hip/hip_runtime.h>
#include <stdint.h>

typedef __attribute__((ext_vector_type(8))) short short8;
typedef __attribute__((ext_vector_type(4))) float f32x4;
typedef __attribute__((ext_vector_type(16))) float f32x16;
typedef __attribute__((ext_vector_type(4))) unsigned int u32x4;
typedef unsigned short u16;
typedef unsigned int u32;

#define NBATCH 8
#define SLEN 1024
#define CDIM 512
#define NHEADS 8
#define HDIM 64
#define MROWS (NBATCH*SLEN)
#define NQKV (NHEADS*3*HDIM)   // 1536
#define QK_SCALE 0.35355339059327373f  // 64^-0.25

__device__ inline u16 f2bf(float f){
  union{float f; uint32_t i;} v; v.f=f;
  uint32_t r = v.i + 0x7fffu + ((v.i>>16)&1u);
  return (u16)(r>>16);
}

// pack two f32 -> bf16x2 word (lo = a, hi = b) via HW cvt_pk (T12 recipe)
__device__ inline u32 pk2(float a, float b){
  u32 r;
  asm("v_cvt_pk_bf16_f32 %0, %1, %2" : "=v"(r) : "v"(a), "v"(b));
  return r;
}

// async global->LDS, 16B per lane; LDS dest = wave-uniform base + lane*16
__device__ __forceinline__ void gld16(const u16* g, u16* l){
  __builtin_amdgcn_global_load_lds(
    (const __attribute__((address_space(1))) void*)g,
    (__attribute__((address_space(3))) void*)l, 16, 0, 0);
}

// ---------------- weight prep: LDS-tiled transpose fp32[K=512][N] -> bf16[N][512] ----
template<int N>
__global__ __launch_bounds__(256) void prep_w(const float* __restrict__ w, u16* __restrict__ wt){
  int tk = blockIdx.x / (N/64), tn = blockIdx.x % (N/64);
  int k0 = tk*64, n0 = tn*64;
  int t = threadIdx.x;
  __shared__ u16 lt[64][72];
  int row = t >> 2, slot = t & 3;
  const float* src = w + (size_t)(k0+row)*N + n0 + slot*16;
  #pragma unroll
  for (int j=0;j<16;++j)
    lt[row][slot*16+j] = f2bf(src[j]);
  __syncthreads();
  u16 tmp[16];
  #pragma unroll
  for (int j=0;j<16;++j) tmp[j] = lt[slot*16+j][row];
  *(u32x4*)(wt + (size_t)(n0+row)*512 + k0 + slot*16)     = *(u32x4*)tmp;
  *(u32x4*)(wt + (size_t)(n0+row)*512 + k0 + slot*16 + 8) = *(u32x4*)(tmp+8);
}

// ---------------- groupnorm stats: one block per (b,g) ----------------
__global__ __launch_bounds__(256) void gn_stats(const float* __restrict__ x, float* __restrict__ stats){
  int bid = blockIdx.x;            // b*32+g
  int b = bid >> 5, g = bid & 31;
  int t = threadIdx.x;
  const float* base = x + (size_t)b*SLEN*CDIM + g*16;
  float s1=0.f, s2=0.f;
  for (int s = t; s < SLEN; s += 256){
    const float4* p = (const float4*)(base + (size_t)s*CDIM);
    #pragma unroll
    for (int j=0;j<4;++j){
      float4 v = p[j];
      s1 += v.x+v.y+v.z+v.w;
      s2 += v.x*v.x + v.y*v.y + v.z*v.z + v.w*v.w;
    }
  }
  #pragma unroll
  for (int m=1;m<64;m<<=1){ s1 += __shfl_xor(s1,m); s2 += __shfl_xor(s2,m); }
  __shared__ float red[8];
  int wid = t>>6;
  if ((t&63)==0){ red[wid*2]=s1; red[wid*2+1]=s2; }
  __syncthreads();
  if (t==0){
    float a=0,c=0;
    #pragma unroll
    for (int w2=0;w2<4;++w2){ a+=red[w2*2]; c+=red[w2*2+1]; }
    float mean = a*(1.f/16384.f);
    float var  = c*(1.f/16384.f) - mean*mean;
    stats[bid*2]   = mean;
    stats[bid*2+1] = rsqrtf(var + 1e-5f);
  }
}

// ---------------- normalize + cast to bf16 ----------------
__global__ __launch_bounds__(256) void norm_cast(const float* __restrict__ x, const float* __restrict__ stats,
                        const float* __restrict__ scale, const float* __restrict__ bias,
                        u16* __restrict__ xn){
  int idx = blockIdx.x*256 + threadIdx.x;   // over 8192*32 (one 16-ch group per thread)
  int m = idx >> 5, g = idx & 31;
  int b = m >> 10;
  float mean = stats[(b*32+g)*2];
  float rstd = stats[(b*32+g)*2+1];
  const float* xp = x + (size_t)m*CDIM + g*16;
  const float* sp = scale + g*16;
  const float* bp = bias + g*16;
  short8 o0, o1;
  #pragma unroll
  for (int j=0;j<16;++j){
    float v = (xp[j]-mean)*rstd*sp[j] + bp[j];
    if (j<8) o0[j] = (short)f2bf(v); else o1[j-8] = (short)f2bf(v);
  }
  short8* dst = (short8*)(xn + (size_t)m*CDIM + g*16);
  dst[0]=o0; dst[1]=o1;
}

// ---------------- GEMM: C = A(MxK) * Bt(NxK)^T, bf16 in, fp32 acc ----------------
#define BM 128
#define BN 128
#define BK 64

template<int EPI, int NT>
__global__ __launch_bounds__(256, 3) void gemm_bf16(
    const u16* __restrict__ A, const u16* __restrict__ Bt,
    const float* __restrict__ bias, const float* __restrict__ resid,
    float* __restrict__ outF,
    u16* __restrict__ qb, u16* __restrict__ kb, u16* __restrict__ vtb)
{
  const int K = CDIM;
  int t = threadIdx.x;
  int l = t & 63, wid = t >> 6;
  int g = l >> 4, c = l & 15;
  int wr = wid >> 1, wc = wid & 1;
  int nwg = gridDim.x;
  int cpx = nwg >> 3;
  int orig = blockIdx.x;
  int swz = (orig & 7)*cpx + (orig >> 3);
  int m0 = (swz / NT) * BM, n0 = (swz % NT) * BN;

  __shared__ __attribute__((aligned(16))) u16 ls[16384];   // 32 KB: lsA[0..8191], lsB[8192..]
  char* lsAc = (char*)ls; char* lsBc = (char*)(ls + 8192);

  f32x4 acc[4][4];
  #pragma unroll
  for (int i=0;i<4;++i)
    #pragma unroll
    for(int j=0;j<4;++j) acc[i][j] = (f32x4)0.f;

  int lrow = l >> 3, slot = l & 7;
  int scol = ((slot ^ lrow) << 3);
  const int KT = K / BK;  // 8
  for (int kt=0; kt<KT; ++kt){
    __syncthreads();
    int kbo = kt*BK;
    #pragma unroll
    for (int q2=0; q2<4; ++q2){
      int row = wid*32 + q2*8 + lrow;
      gld16(A  + (size_t)(m0+row)*K + kbo + scol, ls        + (wid*4+q2)*512);
      gld16(Bt + (size_t)(n0+row)*K + kbo + scol, ls + 8192 + (wid*4+q2)*512);
    }
    asm volatile("s_waitcnt vmcnt(0)" ::: "memory");
    __syncthreads();
    #pragma unroll
    for (int kk=0; kk<2; ++kk){
      short8 af[4], bfr[4];
      #pragma unroll
      for (int i=0;i<4;++i){
        int rowA = wr*64 + i*16 + c;
        af[i]  = *(const short8*)(lsAc + rowA*128 + ((kk*4+g) ^ (rowA&7))*16);
        int rowB = wc*64 + i*16 + c;
        bfr[i] = *(const short8*)(lsBc + rowB*128 + ((kk*4+g) ^ (rowB&7))*16);
      }
      #pragma unroll
      for (int i=0;i<4;++i)
        #pragma unroll
        for (int j=0;j<4;++j)
          acc[i][j] = __builtin_amdgcn_mfma_f32_16x16x32_bf16(af[i], bfr[j], acc[i][j], 0,0,0);
    }
  }

  if (EPI == 0){
    int b = m0 >> 10, s0 = m0 & (SLEN-1);
    __syncthreads();
    u16* lsC = ls;
    #pragma unroll
    for (int i=0;i<4;++i){
      int rl0 = wr*64 + i*16 + g*4;
      #pragma unroll
      for (int j=0;j<4;++j){
        int cl = wc*64 + j*16 + c;
        int gcol = n0 + cl;
        int jj = gcol % 192;
        float sc_ = (jj < 128) ? QK_SCALE : 1.0f;
        float bv = bias[gcol];
        #pragma unroll
        for (int r=0;r<4;++r)
          lsC[(rl0+r)*128 + cl] = f2bf((acc[i][j][r] + bv)*sc_);
      }
    }
    __syncthreads();
    #pragma unroll
    for (int cc=0; cc<8; ++cc){
      int ch = cc*256 + t;
      int rl = ch >> 4, slot2 = ch & 15;
      int cl = slot2*8;
      int gcol = n0 + cl;
      int h = gcol / 192, jj = gcol % 192;
      int s = s0 + rl;
      u32x4 vv = *(const u32x4*)(lsC + rl*128 + cl);
      size_t rowb = ((size_t)(b*NHEADS+h))*SLEN + s;
      if (jj < 64)       __builtin_nontemporal_store(vv, (u32x4*)(qb + rowb*HDIM + jj));
      else if (jj < 128) __builtin_nontemporal_store(vv, (u32x4*)(kb + rowb*HDIM + (jj-64)));
    }
    int blk3 = (n0 >> 7) % 3;
    if (blk3 != 0){
      __syncthreads();
      u16* lsV = ls;            // [64][136] padded
      #pragma unroll
      for (int i=0;i<4;++i){
        int rl0 = wr*64 + i*16 + g*4;
        #pragma unroll
        for (int j=0;j<4;++j){
          int cl = wc*64 + j*16 + c;
          int jj = (n0 + cl) % 192;
          if (jj >= 128){
            #pragma unroll
            for (int r=0;r<4;++r)
              lsV[(jj-128)*136 + rl0 + r] = f2bf(acc[i][j][r] + bias[n0+cl]);
          }
        }
      }
      __syncthreads();
      int hv = (n0 + ((blk3==1)?0:64)) / 192;
      size_t vbase = ((size_t)(b*NHEADS+hv))*HDIM*SLEN;
      #pragma unroll
      for (int cc=0; cc<4; ++cc){
        int chunk = cc*256 + t;
        int d = chunk >> 4, so = (chunk & 15)*8;
        u32x4 vv = *(const u32x4*)(lsV + d*136 + so);
        __builtin_nontemporal_store(vv, (u32x4*)(vtb + vbase + (size_t)d*SLEN + s0 + so));
      }
    }
  } else {
    #pragma unroll
    for (int i=0;i<4;++i){
      int grow = m0 + wr*64 + i*16 + g*4;
      #pragma unroll
      for (int j=0;j<4;++j){
        int gcol = n0 + wc*64 + j*16 + c;
        float bv = bias[gcol];
        #pragma unroll
        for (int r=0;r<4;++r){
          size_t off = (size_t)(grow+r)*CDIM + gcol;
          float rv = __builtin_nontemporal_load(&resid[off]);
          __builtin_nontemporal_store(acc[i][j][r] + bv + rv, &outF[off]);
        }
      }
    }
  }
}

// ---------------- fused flash attention: swapped-QK^T 32x32, 2-stream kv-split ----
// grid: 512 blocks (XCD-swizzled); block: 512 thr = 8 waves.
// qw=wid&3 picks the 32-row q-subtile; st=wid>>2 picks the 512-key half.
// Each stream has its own LDS-staged K/V (2 buffers, stage-early, 1 barrier/tile).
// Cross-stream flash combine at the end (round-8 pattern).
#define PV_KS(PT, QOFF, KS) { \
    u32 A0 = pk2(PT[QOFF+0], PT[QOFF+1]); \
    u32 A1 = pk2(PT[QOFF+2], PT[QOFF+3]); \
    u32 B0 = pk2(PT[QOFF+4], PT[QOFF+5]); \
    u32 B1 = pk2(PT[QOFF+6], PT[QOFF+7]); \
    u32 A0s = __shfl_xor(A0,32), A1s = __shfl_xor(A1,32); \
    u32 B0s = __shfl_xor(B0,32), B1s = __shfl_xor(B1,32); \
    uint4 w; \
    w.x = hi ? B0s : A0;  w.y = hi ? B1s : A1; \
    w.z = hi ? B0  : A0s; w.w = hi ? B1  : A1s; \
    short8 fP; __builtin_memcpy(&fP, &w, 16); \
    o0 = __builtin_amdgcn_mfma_f32_32x32x16_bf16(fV0[KS], fP, o0, 0,0,0); \
    o1 = __builtin_amdgcn_mfma_f32_32x32x16_bf16(fV1[KS], fP, o1, 0,0,0); }

__global__ __launch_bounds__(512, 4) void attn_fused(const u16* __restrict__ qg,
  const u16* __restrict__ kg, const u16* __restrict__ vtg, u16* __restrict__ og)
{
  int bid = blockIdx.x;
  int nid = (bid & 7)*64 + (bid >> 3);   // XCD-contiguous bh
  int bh = nid >> 3, qi = nid & 7;
  int t = threadIdx.x, l = t & 63, wid = t >> 6;
  int qw = wid & 3, st = wid >> 2;
  int q = l & 31, hi = l >> 5;
  int q0 = qi*128 + qw*32;

  // 64KB: K streams [st][buf][64][64] at smem[0..16383], V streams at +16384 (u16 units)
  __shared__ __attribute__((aligned(16))) u16 smem[32768];
  u16* klp = smem;
  u16* vlp = smem + 16384;

  const u16* qrow = qg + ((size_t)bh*SLEN + q0 + q)*HDIM + hi*8;
  short8 fQ[4];
  #pragma unroll
  for (int ds=0; ds<4; ++ds) fQ[ds] = *(const short8*)(qrow + ds*16);

  f32x16 o0, o1;
  #pragma unroll
  for (int r=0;r<16;++r){ o0[r]=0.f; o1[r]=0.f; }
  float mr = -1e30f, lsum = 0.f;

  const u16* kbase = kg  + (size_t)bh*SLEN*HDIM + (size_t)st*512*HDIM;
  const u16* vbase = vtg + (size_t)bh*HDIM*SLEN + st*512;
  // staging lane geometry: each wave stages 1/4 of its stream's tile (2 chunks K + 2 V).
  // LDS[row][slot] = global[row][slot ^ (row&7)]  (pre-swizzled source)
  int srow = l >> 3, sslot = l & 7;
  int scol8 = ((sslot ^ srow) << 3);   // u16 offset within 64-col row

#define STAGE(BUF, KV) { \
    _Pragma("unroll") \
    for (int j=0;j<2;++j){ \
      int row = qw*16 + j*8 + srow; \
      int chunk = qw*2 + j; \
      gld16(kbase + (size_t)((KV)*64 + row)*HDIM + scol8, klp + st*8192 + (BUF)*4096 + chunk*512); \
      gld16(vbase + (size_t)row*SLEN + (KV)*64 + scol8,   vlp + st*8192 + (BUF)*4096 + chunk*512); \
    } }

  STAGE(0, 0)

  int sl_q = q & 7;
  for (int kv=0; kv<8; ++kv){
    int cur = kv & 1;
    asm volatile("s_waitcnt vmcnt(0)" ::: "memory");  // tile kv landed (covered by prior compute)
    __syncthreads();
    if (kv < 7) STAGE(cur^1, kv+1)                    // overwrites tile kv-1's buffer (reads done pre-barrier)
    const u16* kb_ = klp + st*8192 + cur*4096;
    const u16* vb_ = vlp + st*8192 + cur*4096;
    // K fragments from LDS (swizzled)
    short8 fK0[4], fK1[4];
    #pragma unroll
    for (int ds=0; ds<4; ++ds){
      int sl = ((ds*2+hi) ^ sl_q) << 3;
      fK0[ds] = *(const short8*)(kb_ + q*64 + sl);
      fK1[ds] = *(const short8*)(kb_ + (q+32)*64 + sl);
    }
    f32x16 p0, p1;
    #pragma unroll
    for (int r=0;r<16;++r){ p0[r]=0.f; p1[r]=0.f; }
    __builtin_amdgcn_s_setprio(1);
    #pragma unroll
    for (int ds=0; ds<4; ++ds){
      p0 = __builtin_amdgcn_mfma_f32_32x32x16_bf16(fK0[ds], fQ[ds], p0, 0,0,0);
      p1 = __builtin_amdgcn_mfma_f32_32x32x16_bf16(fK1[ds], fQ[ds], p1, 0,0,0);
    }
    __builtin_amdgcn_s_setprio(0);
    // ---- online softmax with defer-max (THR=8) ----
    float a8[8];
    #pragma unroll
    for (int r=0;r<8;++r)
      a8[r] = fmaxf(fmaxf(p0[r],p0[r+8]), fmaxf(p1[r],p1[r+8]));
    #pragma unroll
    for (int s=4;s>0;s>>=1)
      #pragma unroll
      for (int r=0;r<4;++r) if (r<s) a8[r] = fmaxf(a8[r], a8[r+s]);
    float tmax = fmaxf(a8[0], __shfl_xor(a8[0], 32));
    if (!__all(tmax <= mr + 8.0f)){
      float mn = fmaxf(mr, tmax);
      float alpha = __expf(mr - mn);
      mr = mn;
      lsum *= alpha;
      #pragma unroll
      for (int r=0;r<16;++r){ o0[r]*=alpha; o1[r]*=alpha; }
    }
    #pragma unroll
    for (int r=0;r<16;++r){ p0[r] = __expf(p0[r]-mr); p1[r] = __expf(p1[r]-mr); }
    // V fragments from LDS (swizzled) — issue while sum-tree runs
    short8 fV0[4], fV1[4];
    #pragma unroll
    for (int ks=0; ks<4; ++ks){
      int sl = ((ks*2+hi) ^ sl_q) << 3;
      fV0[ks] = *(const short8*)(vb_ + q*64 + sl);
      fV1[ks] = *(const short8*)(vb_ + (q+32)*64 + sl);
    }
    float s8[8];
    #pragma unroll
    for (int r=0;r<8;++r) s8[r] = (p0[r]+p0[r+8]) + (p1[r]+p1[r+8]);
    #pragma unroll
    for (int s=4;s>0;s>>=1)
      #pragma unroll
      for (int r=0;r<4;++r) if (r<s) s8[r] += s8[r+s];
    float rs = s8[0] + __shfl_xor(s8[0], 32);
    lsum += rs;
    __builtin_amdgcn_s_setprio(1);
    PV_KS(p0, 0, 0)
    PV_KS(p0, 8, 1)
    PV_KS(p1, 0, 2)
    PV_KS(p1, 8, 3)
    __builtin_amdgcn_s_setprio(0);
  }

  // ---- cross-stream flash combine (pairs st=0 <-> st=1, same qw) ----
  __syncthreads();                       // all in-loop LDS traffic done; overlay combine buf
  float* cls = (float*)smem;             // [4][64][35] f32 = 35840B
  if (st == 1){
    float* dst = cls + (qw*64 + l)*35;
    #pragma unroll
    for (int r=0;r<16;++r){ dst[r] = o0[r]; dst[16+r] = o1[r]; }
    dst[32] = mr; dst[33] = lsum;
  }
  __syncthreads();
  if (st == 0){
    const float* src = cls + (qw*64 + l)*35;
    float m2 = src[32], l2 = src[33];
    float M = fmaxf(mr, m2);
    float a1 = __expf(mr - M), a2 = __expf(m2 - M);
    float L = lsum*a1 + l2*a2;
    float inv = 1.f / L;
    int b = bh >> 3, h = bh & 7;
    u16* obase = og + ((size_t)b*SLEN + q0 + q)*CDIM + h*HDIM;
    #pragma unroll
    for (int pr=0; pr<8; ++pr){
      int d = ((2*pr)&3) + 8*(pr>>1) + 4*hi;
      float v0 = (o0[2*pr  ]*a1 + src[2*pr  ]*a2)*inv;
      float v1 = (o0[2*pr+1]*a1 + src[2*pr+1]*a2)*inv;
      *(u32*)(obase + d) = pk2(v0, v1);
      float w0 = (o1[2*pr  ]*a1 + src[16+2*pr  ]*a2)*inv;
      float w1 = (o1[2*pr+1]*a1 + src[16+2*pr+1]*a2)*inv;
      *(u32*)(obase + 32 + d) = pk2(w0, w1);
    }
  }
}

extern "C" void kernel_launch(void* const* d_in, const int* in_sizes, int n_in,
                              void* d_out, int out_size, void* d_ws, size_t ws_size,
                              hipStream_t stream){
  const float* x      = (const float*)d_in[0];
  const float* nscale = (const float*)d_in[1];
  const float* nbias  = (const float*)d_in[2];
  const float* wqkv   = (const float*)d_in[3];
  const float* bqkv   = (const float*)d_in[4];
  const float* wout   = (const float*)d_in[5];
  const float* bout   = (const float*)d_in[6];
  float* out = (float*)d_out;

  char* ws = (char*)d_ws;
  size_t off = 0;
  auto alloc = [&](size_t bytes){ void* p = ws + off; off += (bytes + 255) & ~255ull; return p; };
  float* stats  = (float*)alloc(256*2*sizeof(float));
  u16* wqkv_t = (u16*)alloc((size_t)NQKV*CDIM*2);
  u16* wout_t = (u16*)alloc((size_t)CDIM*CDIM*2);
  u16* xn     = (u16*)alloc((size_t)MROWS*CDIM*2);
  u16* qb     = (u16*)alloc((size_t)MROWS*CDIM*2);
  u16* kb     = (u16*)alloc((size_t)MROWS*CDIM*2);
  u16* vtb    = (u16*)alloc((size_t)MROWS*CDIM*2);
  u16* ob     = (u16*)alloc((size_t)MROWS*CDIM*2);

  prep_w<NQKV><<<dim3(8*(NQKV/64)), dim3(256), 0, stream>>>(wqkv, wqkv_t);
  prep_w<CDIM><<<dim3(8*(CDIM/64)), dim3(256), 0, stream>>>(wout, wout_t);
  gn_stats <<<dim3(256), dim3(256), 0, stream>>>(x, stats);
  norm_cast<<<dim3((MROWS*32)/256), dim3(256), 0, stream>>>(x, stats, nscale, nbias, xn);
  gemm_bf16<0,12><<<dim3(768), dim3(256), 0, stream>>>(xn, wqkv_t, bqkv, nullptr, nullptr, qb, kb, vtb);
  attn_fused<<<dim3(512), dim3(512), 0, stream>>>(qb, kb, vtb, ob);
  gemm_bf16<1,4><<<dim3(256), dim3(256), 0, stream>>>(ob, wout_t, bout, x, out, nullptr, nullptr, nullptr);
}

// Round 12
// 99.838 us; speedup vs baseline: 1.0772x; 1.0772x over previous
//
#include <hip/hip_runtime.h>
#include <stdint.h>

typedef __attribute__((ext_vector_type(8))) short short8;
typedef __attribute__((ext_vector_type(4))) float f32x4;
typedef __attribute__((ext_vector_type(16))) float f32x16;
typedef __attribute__((ext_vector_type(4))) unsigned int u32x4;
typedef unsigned short u16;
typedef unsigned int u32;

#define NBATCH 8
#define SLEN 1024
#define CDIM 512
#define NHEADS 8
#define HDIM 64
#define MROWS (NBATCH*SLEN)
#define NQKV (NHEADS*3*HDIM)   // 1536
#define QK_SCALE 0.35355339059327373f  // 64^-0.25

__device__ inline u16 f2bf(float f){
  union{float f; uint32_t i;} v; v.f=f;
  uint32_t r = v.i + 0x7fffu + ((v.i>>16)&1u);
  return (u16)(r>>16);
}

// pack two f32 -> bf16x2 word (lo = a, hi = b) via HW cvt_pk (T12 recipe)
__device__ inline u32 pk2(float a, float b){
  u32 r;
  asm("v_cvt_pk_bf16_f32 %0, %1, %2" : "=v"(r) : "v"(a), "v"(b));
  return r;
}

// async global->LDS, 16B per lane; LDS dest = wave-uniform base + lane*16
__device__ __forceinline__ void gld16(const u16* g, u16* l){
  __builtin_amdgcn_global_load_lds(
    (const __attribute__((address_space(1))) void*)g,
    (__attribute__((address_space(3))) void*)l, 16, 0, 0);
}

// ---------------- weight prep: LDS-tiled transpose fp32[K=512][N] -> bf16[N][512] ----
template<int N>
__global__ __launch_bounds__(256) void prep_w(const float* __restrict__ w, u16* __restrict__ wt){
  int tk = blockIdx.x / (N/64), tn = blockIdx.x % (N/64);
  int k0 = tk*64, n0 = tn*64;
  int t = threadIdx.x;
  __shared__ u16 lt[64][72];
  int row = t >> 2, slot = t & 3;
  const float* src = w + (size_t)(k0+row)*N + n0 + slot*16;
  #pragma unroll
  for (int j=0;j<16;++j)
    lt[row][slot*16+j] = f2bf(src[j]);
  __syncthreads();
  u16 tmp[16];
  #pragma unroll
  for (int j=0;j<16;++j) tmp[j] = lt[slot*16+j][row];
  *(u32x4*)(wt + (size_t)(n0+row)*512 + k0 + slot*16)     = *(u32x4*)tmp;
  *(u32x4*)(wt + (size_t)(n0+row)*512 + k0 + slot*16 + 8) = *(u32x4*)(tmp+8);
}

// ---------------- groupnorm stats: one block per (b,g) ----------------
__global__ __launch_bounds__(256) void gn_stats(const float* __restrict__ x, float* __restrict__ stats){
  int bid = blockIdx.x;            // b*32+g
  int b = bid >> 5, g = bid & 31;
  int t = threadIdx.x;
  const float* base = x + (size_t)b*SLEN*CDIM + g*16;
  float s1=0.f, s2=0.f;
  for (int s = t; s < SLEN; s += 256){
    const float4* p = (const float4*)(base + (size_t)s*CDIM);
    #pragma unroll
    for (int j=0;j<4;++j){
      float4 v = p[j];
      s1 += v.x+v.y+v.z+v.w;
      s2 += v.x*v.x + v.y*v.y + v.z*v.z + v.w*v.w;
    }
  }
  #pragma unroll
  for (int m=1;m<64;m<<=1){ s1 += __shfl_xor(s1,m); s2 += __shfl_xor(s2,m); }
  __shared__ float red[8];
  int wid = t>>6;
  if ((t&63)==0){ red[wid*2]=s1; red[wid*2+1]=s2; }
  __syncthreads();
  if (t==0){
    float a=0,c=0;
    #pragma unroll
    for (int w2=0;w2<4;++w2){ a+=red[w2*2]; c+=red[w2*2+1]; }
    float mean = a*(1.f/16384.f);
    float var  = c*(1.f/16384.f) - mean*mean;
    stats[bid*2]   = mean;
    stats[bid*2+1] = rsqrtf(var + 1e-5f);
  }
}

// ---------------- normalize + cast to bf16 ----------------
__global__ __launch_bounds__(256) void norm_cast(const float* __restrict__ x, const float* __restrict__ stats,
                        const float* __restrict__ scale, const float* __restrict__ bias,
                        u16* __restrict__ xn){
  int idx = blockIdx.x*256 + threadIdx.x;   // over 8192*32 (one 16-ch group per thread)
  int m = idx >> 5, g = idx & 31;
  int b = m >> 10;
  float mean = stats[(b*32+g)*2];
  float rstd = stats[(b*32+g)*2+1];
  const float* xp = x + (size_t)m*CDIM + g*16;
  const float* sp = scale + g*16;
  const float* bp = bias + g*16;
  short8 o0, o1;
  #pragma unroll
  for (int j=0;j<16;++j){
    float v = (xp[j]-mean)*rstd*sp[j] + bp[j];
    if (j<8) o0[j] = (short)f2bf(v); else o1[j-8] = (short)f2bf(v);
  }
  short8* dst = (short8*)(xn + (size_t)m*CDIM + g*16);
  dst[0]=o0; dst[1]=o1;
}

// ---------------- GEMM: C = A(MxK) * Bt(NxK)^T, bf16 in, fp32 acc ----------------
#define BM 128
#define BN 128
#define BK 64

template<int EPI, int NT>
__global__ __launch_bounds__(256, 3) void gemm_bf16(
    const u16* __restrict__ A, const u16* __restrict__ Bt,
    const float* __restrict__ bias, const float* __restrict__ resid,
    float* __restrict__ outF,
    u16* __restrict__ qb, u16* __restrict__ kb, u16* __restrict__ vtb)
{
  const int K = CDIM;
  int t = threadIdx.x;
  int l = t & 63, wid = t >> 6;
  int g = l >> 4, c = l & 15;
  int wr = wid >> 1, wc = wid & 1;
  int nwg = gridDim.x;
  int cpx = nwg >> 3;
  int orig = blockIdx.x;
  int swz = (orig & 7)*cpx + (orig >> 3);
  int m0 = (swz / NT) * BM, n0 = (swz % NT) * BN;

  __shared__ __attribute__((aligned(16))) u16 ls[16384];   // 32 KB: lsA[0..8191], lsB[8192..]
  char* lsAc = (char*)ls; char* lsBc = (char*)(ls + 8192);

  f32x4 acc[4][4];
  #pragma unroll
  for (int i=0;i<4;++i)
    #pragma unroll
    for(int j=0;j<4;++j) acc[i][j] = (f32x4)0.f;

  int lrow = l >> 3, slot = l & 7;
  int scol = ((slot ^ lrow) << 3);
  const int KT = K / BK;  // 8
  for (int kt=0; kt<KT; ++kt){
    __syncthreads();
    int kbo = kt*BK;
    #pragma unroll
    for (int q2=0; q2<4; ++q2){
      int row = wid*32 + q2*8 + lrow;
      gld16(A  + (size_t)(m0+row)*K + kbo + scol, ls        + (wid*4+q2)*512);
      gld16(Bt + (size_t)(n0+row)*K + kbo + scol, ls + 8192 + (wid*4+q2)*512);
    }
    asm volatile("s_waitcnt vmcnt(0)" ::: "memory");
    __syncthreads();
    #pragma unroll
    for (int kk=0; kk<2; ++kk){
      short8 af[4], bfr[4];
      #pragma unroll
      for (int i=0;i<4;++i){
        int rowA = wr*64 + i*16 + c;
        af[i]  = *(const short8*)(lsAc + rowA*128 + ((kk*4+g) ^ (rowA&7))*16);
        int rowB = wc*64 + i*16 + c;
        bfr[i] = *(const short8*)(lsBc + rowB*128 + ((kk*4+g) ^ (rowB&7))*16);
      }
      #pragma unroll
      for (int i=0;i<4;++i)
        #pragma unroll
        for (int j=0;j<4;++j)
          acc[i][j] = __builtin_amdgcn_mfma_f32_16x16x32_bf16(af[i], bfr[j], acc[i][j], 0,0,0);
    }
  }

  if (EPI == 0){
    int b = m0 >> 10, s0 = m0 & (SLEN-1);
    __syncthreads();
    u16* lsC = ls;
    #pragma unroll
    for (int i=0;i<4;++i){
      int rl0 = wr*64 + i*16 + g*4;
      #pragma unroll
      for (int j=0;j<4;++j){
        int cl = wc*64 + j*16 + c;
        int gcol = n0 + cl;
        int jj = gcol % 192;
        float sc_ = (jj < 128) ? QK_SCALE : 1.0f;
        float bv = bias[gcol];
        #pragma unroll
        for (int r=0;r<4;++r)
          lsC[(rl0+r)*128 + cl] = f2bf((acc[i][j][r] + bv)*sc_);
      }
    }
    __syncthreads();
    #pragma unroll
    for (int cc=0; cc<8; ++cc){
      int ch = cc*256 + t;
      int rl = ch >> 4, slot2 = ch & 15;
      int cl = slot2*8;
      int gcol = n0 + cl;
      int h = gcol / 192, jj = gcol % 192;
      int s = s0 + rl;
      u32x4 vv = *(const u32x4*)(lsC + rl*128 + cl);
      size_t rowb = ((size_t)(b*NHEADS+h))*SLEN + s;
      if (jj < 64)       __builtin_nontemporal_store(vv, (u32x4*)(qb + rowb*HDIM + jj));
      else if (jj < 128) __builtin_nontemporal_store(vv, (u32x4*)(kb + rowb*HDIM + (jj-64)));
    }
    int blk3 = (n0 >> 7) % 3;
    if (blk3 != 0){
      __syncthreads();
      u16* lsV = ls;            // [64][136] padded
      #pragma unroll
      for (int i=0;i<4;++i){
        int rl0 = wr*64 + i*16 + g*4;
        #pragma unroll
        for (int j=0;j<4;++j){
          int cl = wc*64 + j*16 + c;
          int jj = (n0 + cl) % 192;
          if (jj >= 128){
            #pragma unroll
            for (int r=0;r<4;++r)
              lsV[(jj-128)*136 + rl0 + r] = f2bf(acc[i][j][r] + bias[n0+cl]);
          }
        }
      }
      __syncthreads();
      int hv = (n0 + ((blk3==1)?0:64)) / 192;
      size_t vbase = ((size_t)(b*NHEADS+hv))*HDIM*SLEN;
      #pragma unroll
      for (int cc=0; cc<4; ++cc){
        int chunk = cc*256 + t;
        int d = chunk >> 4, so = (chunk & 15)*8;
        u32x4 vv = *(const u32x4*)(lsV + d*136 + so);
        __builtin_nontemporal_store(vv, (u32x4*)(vtb + vbase + (size_t)d*SLEN + s0 + so));
      }
    }
  } else {
    #pragma unroll
    for (int i=0;i<4;++i){
      int grow = m0 + wr*64 + i*16 + g*4;
      #pragma unroll
      for (int j=0;j<4;++j){
        int gcol = n0 + wc*64 + j*16 + c;
        float bv = bias[gcol];
        #pragma unroll
        for (int r=0;r<4;++r){
          size_t off = (size_t)(grow+r)*CDIM + gcol;
          float rv = __builtin_nontemporal_load(&resid[off]);
          __builtin_nontemporal_store(acc[i][j][r] + bv + rv, &outF[off]);
        }
      }
    }
  }
}

// ---------------- fused flash attention: swapped-QK^T 32x32, 2-stream kv-split ----
// grid: 512 blocks (XCD-swizzled); block: 512 thr = 8 waves.
// qw=wid&3 picks the 32-row q-subtile; st=wid>>2 picks the 512-key half.
// Each stream has its own LDS-staged K/V (2 buffers, stage-early, 1 barrier/tile).
// Cross-stream flash combine at the end (round-8 pattern).
// NOTE: launch_bounds arg2 behaves as BLOCKS/CU on this toolchain (r11 post-mortem):
// (512,2) => 2 blocks/CU = 16 waves/CU = 4 waves/EU => 128-VGPR cap.
#define PV_KS(PT, QOFF, KS) { \
    u32 A0 = pk2(PT[QOFF+0], PT[QOFF+1]); \
    u32 A1 = pk2(PT[QOFF+2], PT[QOFF+3]); \
    u32 B0 = pk2(PT[QOFF+4], PT[QOFF+5]); \
    u32 B1 = pk2(PT[QOFF+6], PT[QOFF+7]); \
    u32 A0s = __shfl_xor(A0,32), A1s = __shfl_xor(A1,32); \
    u32 B0s = __shfl_xor(B0,32), B1s = __shfl_xor(B1,32); \
    uint4 w; \
    w.x = hi ? B0s : A0;  w.y = hi ? B1s : A1; \
    w.z = hi ? B0  : A0s; w.w = hi ? B1  : A1s; \
    short8 fP; __builtin_memcpy(&fP, &w, 16); \
    o0 = __builtin_amdgcn_mfma_f32_32x32x16_bf16(fV0[KS], fP, o0, 0,0,0); \
    o1 = __builtin_amdgcn_mfma_f32_32x32x16_bf16(fV1[KS], fP, o1, 0,0,0); }

__global__ __launch_bounds__(512, 2) void attn_fused(const u16* __restrict__ qg,
  const u16* __restrict__ kg, const u16* __restrict__ vtg, u16* __restrict__ og)
{
  int bid = blockIdx.x;
  int nid = (bid & 7)*64 + (bid >> 3);   // XCD-contiguous bh
  int bh = nid >> 3, qi = nid & 7;
  int t = threadIdx.x, l = t & 63, wid = t >> 6;
  int qw = wid & 3, st = wid >> 2;
  int q = l & 31, hi = l >> 5;
  int q0 = qi*128 + qw*32;

  // 64KB: K streams [st][buf][64][64] at smem[0..16383], V streams at +16384 (u16 units)
  __shared__ __attribute__((aligned(16))) u16 smem[32768];
  u16* klp = smem;
  u16* vlp = smem + 16384;

  const u16* qrow = qg + ((size_t)bh*SLEN + q0 + q)*HDIM + hi*8;
  short8 fQ[4];
  #pragma unroll
  for (int ds=0; ds<4; ++ds) fQ[ds] = *(const short8*)(qrow + ds*16);

  f32x16 o0, o1;
  #pragma unroll
  for (int r=0;r<16;++r){ o0[r]=0.f; o1[r]=0.f; }
  float mr = -1e30f, lsum = 0.f;

  const u16* kbase = kg  + (size_t)bh*SLEN*HDIM + (size_t)st*512*HDIM;
  const u16* vbase = vtg + (size_t)bh*HDIM*SLEN + st*512;
  // staging lane geometry: each wave stages 1/4 of its stream's tile (2 chunks K + 2 V).
  // LDS[row][slot] = global[row][slot ^ (row&7)]  (pre-swizzled source)
  int srow = l >> 3, sslot = l & 7;
  int scol8 = ((sslot ^ srow) << 3);   // u16 offset within 64-col row

#define STAGE(BUF, KV) { \
    _Pragma("unroll") \
    for (int j=0;j<2;++j){ \
      int row = qw*16 + j*8 + srow; \
      int chunk = qw*2 + j; \
      gld16(kbase + (size_t)((KV)*64 + row)*HDIM + scol8, klp + st*8192 + (BUF)*4096 + chunk*512); \
      gld16(vbase + (size_t)row*SLEN + (KV)*64 + scol8,   vlp + st*8192 + (BUF)*4096 + chunk*512); \
    } }

  STAGE(0, 0)

  int sl_q = q & 7;
  for (int kv=0; kv<8; ++kv){
    int cur = kv & 1;
    asm volatile("s_waitcnt vmcnt(0)" ::: "memory");  // tile kv landed (covered by prior compute)
    __syncthreads();
    if (kv < 7) STAGE(cur^1, kv+1)                    // overwrites tile kv-1's buffer (reads done pre-barrier)
    const u16* kb_ = klp + st*8192 + cur*4096;
    const u16* vb_ = vlp + st*8192 + cur*4096;
    // K fragments from LDS (swizzled)
    short8 fK0[4], fK1[4];
    #pragma unroll
    for (int ds=0; ds<4; ++ds){
      int sl = ((ds*2+hi) ^ sl_q) << 3;
      fK0[ds] = *(const short8*)(kb_ + q*64 + sl);
      fK1[ds] = *(const short8*)(kb_ + (q+32)*64 + sl);
    }
    f32x16 p0, p1;
    #pragma unroll
    for (int r=0;r<16;++r){ p0[r]=0.f; p1[r]=0.f; }
    __builtin_amdgcn_s_setprio(1);
    #pragma unroll
    for (int ds=0; ds<4; ++ds){
      p0 = __builtin_amdgcn_mfma_f32_32x32x16_bf16(fK0[ds], fQ[ds], p0, 0,0,0);
      p1 = __builtin_amdgcn_mfma_f32_32x32x16_bf16(fK1[ds], fQ[ds], p1, 0,0,0);
    }
    __builtin_amdgcn_s_setprio(0);
    // ---- online softmax with defer-max (THR=8) ----
    float a8[8];
    #pragma unroll
    for (int r=0;r<8;++r)
      a8[r] = fmaxf(fmaxf(p0[r],p0[r+8]), fmaxf(p1[r],p1[r+8]));
    #pragma unroll
    for (int s=4;s>0;s>>=1)
      #pragma unroll
      for (int r=0;r<4;++r) if (r<s) a8[r] = fmaxf(a8[r], a8[r+s]);
    float tmax = fmaxf(a8[0], __shfl_xor(a8[0], 32));
    if (!__all(tmax <= mr + 8.0f)){
      float mn = fmaxf(mr, tmax);
      float alpha = __expf(mr - mn);
      mr = mn;
      lsum *= alpha;
      #pragma unroll
      for (int r=0;r<16;++r){ o0[r]*=alpha; o1[r]*=alpha; }
    }
    #pragma unroll
    for (int r=0;r<16;++r){ p0[r] = __expf(p0[r]-mr); p1[r] = __expf(p1[r]-mr); }
    // V fragments from LDS (swizzled) — issue while sum-tree runs
    short8 fV0[4], fV1[4];
    #pragma unroll
    for (int ks=0; ks<4; ++ks){
      int sl = ((ks*2+hi) ^ sl_q) << 3;
      fV0[ks] = *(const short8*)(vb_ + q*64 + sl);
      fV1[ks] = *(const short8*)(vb_ + (q+32)*64 + sl);
    }
    float s8[8];
    #pragma unroll
    for (int r=0;r<8;++r) s8[r] = (p0[r]+p0[r+8]) + (p1[r]+p1[r+8]);
    #pragma unroll
    for (int s=4;s>0;s>>=1)
      #pragma unroll
      for (int r=0;r<4;++r) if (r<s) s8[r] += s8[r+s];
    float rs = s8[0] + __shfl_xor(s8[0], 32);
    lsum += rs;
    __builtin_amdgcn_s_setprio(1);
    PV_KS(p0, 0, 0)
    PV_KS(p0, 8, 1)
    PV_KS(p1, 0, 2)
    PV_KS(p1, 8, 3)
    __builtin_amdgcn_s_setprio(0);
  }

  // ---- cross-stream flash combine (pairs st=0 <-> st=1, same qw) ----
  __syncthreads();                       // all in-loop LDS traffic done; overlay combine buf
  float* cls = (float*)smem;             // [4][64][35] f32 = 35840B
  if (st == 1){
    float* dst = cls + (qw*64 + l)*35;
    #pragma unroll
    for (int r=0;r<16;++r){ dst[r] = o0[r]; dst[16+r] = o1[r]; }
    dst[32] = mr; dst[33] = lsum;
  }
  __syncthreads();
  if (st == 0){
    const float* src = cls + (qw*64 + l)*35;
    float m2 = src[32], l2 = src[33];
    float M = fmaxf(mr, m2);
    float a1 = __expf(mr - M), a2 = __expf(m2 - M);
    float L = lsum*a1 + l2*a2;
    float inv = 1.f / L;
    int b = bh >> 3, h = bh & 7;
    u16* obase = og + ((size_t)b*SLEN + q0 + q)*CDIM + h*HDIM;
    #pragma unroll
    for (int pr=0; pr<8; ++pr){
      int d = ((2*pr)&3) + 8*(pr>>1) + 4*hi;
      float v0 = (o0[2*pr  ]*a1 + src[2*pr  ]*a2)*inv;
      float v1 = (o0[2*pr+1]*a1 + src[2*pr+1]*a2)*inv;
      *(u32*)(obase + d) = pk2(v0, v1);
      float w0 = (o1[2*pr  ]*a1 + src[16+2*pr  ]*a2)*inv;
      float w1 = (o1[2*pr+1]*a1 + src[16+2*pr+1]*a2)*inv;
      *(u32*)(obase + 32 + d) = pk2(w0, w1);
    }
  }
}

extern "C" void kernel_launch(void* const* d_in, const int* in_sizes, int n_in,
                              void* d_out, int out_size, void* d_ws, size_t ws_size,
                              hipStream_t stream){
  const float* x      = (const float*)d_in[0];
  const float* nscale = (const float*)d_in[1];
  const float* nbias  = (const float*)d_in[2];
  const float* wqkv   = (const float*)d_in[3];
  const float* bqkv   = (const float*)d_in[4];
  const float* wout   = (const float*)d_in[5];
  const float* bout   = (const float*)d_in[6];
  float* out = (float*)d_out;

  char* ws = (char*)d_ws;
  size_t off = 0;
  auto alloc = [&](size_t bytes){ void* p = ws + off; off += (bytes + 255) & ~255ull; return p; };
  float* stats  = (float*)alloc(256*2*sizeof(float));
  u16* wqkv_t = (u16*)alloc((size_t)NQKV*CDIM*2);
  u16* wout_t = (u16*)alloc((size_t)CDIM*CDIM*2);
  u16* xn     = (u16*)alloc((size_t)MROWS*CDIM*2);
  u16* qb     = (u16*)alloc((size_t)MROWS*CDIM*2);
  u16* kb     = (u16*)alloc((size_t)MROWS*CDIM*2);
  u16* vtb    = (u16*)alloc((size_t)MROWS*CDIM*2);
  u16* ob     = (u16*)alloc((size_t)MROWS*CDIM*2);

  prep_w<NQKV><<<dim3(8*(NQKV/64)), dim3(256), 0, stream>>>(wqkv, wqkv_t);
  prep_w<CDIM><<<dim3(8*(CDIM/64)), dim3(256), 0, stream>>>(wout, wout_t);
  gn_stats <<<dim3(256), dim3(256), 0, stream>>>(x, stats);
  norm_cast<<<dim3((MROWS*32)/256), dim3(256), 0, stream>>>(x, stats, nscale, nbias, xn);
  gemm_bf16<0,12><<<dim3(768), dim3(256), 0, stream>>>(xn, wqkv_t, bqkv, nullptr, nullptr, qb, kb, vtb);
  attn_fused<<<dim3(512), dim3(512), 0, stream>>>(qb, kb, vtb, ob);
  gemm_bf16<1,4><<<dim3(256), dim3(256), 0, stream>>>(ob, wout_t, bout, x, out, nullptr, nullptr, nullptr);
}

// Round 13
// 95.187 us; speedup vs baseline: 1.1298x; 1.0489x over previous
//
#include <hip/hip_runtime.h>
#include <stdint.h>

typedef __attribute__((ext_vector_type(8))) short short8;
typedef __attribute__((ext_vector_type(4))) float f32x4;
typedef __attribute__((ext_vector_type(16))) float f32x16;
typedef __attribute__((ext_vector_type(4))) unsigned int u32x4;
typedef unsigned short u16;
typedef unsigned int u32;

#define NBATCH 8
#define SLEN 1024
#define CDIM 512
#define NHEADS 8
#define HDIM 64
#define MROWS (NBATCH*SLEN)
#define NQKV (NHEADS*3*HDIM)   // 1536
#define QK_SCALE 0.35355339059327373f  // 64^-0.25

__device__ inline u16 f2bf(float f){
  union{float f; uint32_t i;} v; v.f=f;
  uint32_t r = v.i + 0x7fffu + ((v.i>>16)&1u);
  return (u16)(r>>16);
}

// pack two f32 -> bf16x2 word (lo = a, hi = b) via HW cvt_pk (T12 recipe)
__device__ inline u32 pk2(float a, float b){
  u32 r;
  asm("v_cvt_pk_bf16_f32 %0, %1, %2" : "=v"(r) : "v"(a), "v"(b));
  return r;
}

// async global->LDS, 16B per lane; LDS dest = wave-uniform base + lane*16
__device__ __forceinline__ void gld16(const u16* g, u16* l){
  __builtin_amdgcn_global_load_lds(
    (const __attribute__((address_space(1))) void*)g,
    (__attribute__((address_space(3))) void*)l, 16, 0, 0);
}

// ---------------- weight prep: LDS-tiled transpose fp32[K=512][N] -> bf16[N][512] ----
template<int N>
__global__ __launch_bounds__(256) void prep_w(const float* __restrict__ w, u16* __restrict__ wt){
  int tk = blockIdx.x / (N/64), tn = blockIdx.x % (N/64);
  int k0 = tk*64, n0 = tn*64;
  int t = threadIdx.x;
  __shared__ u16 lt[64][72];
  int row = t >> 2, slot = t & 3;
  const float* src = w + (size_t)(k0+row)*N + n0 + slot*16;
  #pragma unroll
  for (int j=0;j<16;++j)
    lt[row][slot*16+j] = f2bf(src[j]);
  __syncthreads();
  u16 tmp[16];
  #pragma unroll
  for (int j=0;j<16;++j) tmp[j] = lt[slot*16+j][row];
  *(u32x4*)(wt + (size_t)(n0+row)*512 + k0 + slot*16)     = *(u32x4*)tmp;
  *(u32x4*)(wt + (size_t)(n0+row)*512 + k0 + slot*16 + 8) = *(u32x4*)(tmp+8);
}

// ---------------- groupnorm stats: one block per (b,g) ----------------
__global__ __launch_bounds__(256) void gn_stats(const float* __restrict__ x, float* __restrict__ stats){
  int bid = blockIdx.x;            // b*32+g
  int b = bid >> 5, g = bid & 31;
  int t = threadIdx.x;
  const float* base = x + (size_t)b*SLEN*CDIM + g*16;
  float s1=0.f, s2=0.f;
  for (int s = t; s < SLEN; s += 256){
    const float4* p = (const float4*)(base + (size_t)s*CDIM);
    #pragma unroll
    for (int j=0;j<4;++j){
      float4 v = p[j];
      s1 += v.x+v.y+v.z+v.w;
      s2 += v.x*v.x + v.y*v.y + v.z*v.z + v.w*v.w;
    }
  }
  #pragma unroll
  for (int m=1;m<64;m<<=1){ s1 += __shfl_xor(s1,m); s2 += __shfl_xor(s2,m); }
  __shared__ float red[8];
  int wid = t>>6;
  if ((t&63)==0){ red[wid*2]=s1; red[wid*2+1]=s2; }
  __syncthreads();
  if (t==0){
    float a=0,c=0;
    #pragma unroll
    for (int w2=0;w2<4;++w2){ a+=red[w2*2]; c+=red[w2*2+1]; }
    float mean = a*(1.f/16384.f);
    float var  = c*(1.f/16384.f) - mean*mean;
    stats[bid*2]   = mean;
    stats[bid*2+1] = rsqrtf(var + 1e-5f);
  }
}

// ---------------- normalize + cast to bf16 ----------------
__global__ __launch_bounds__(256) void norm_cast(const float* __restrict__ x, const float* __restrict__ stats,
                        const float* __restrict__ scale, const float* __restrict__ bias,
                        u16* __restrict__ xn){
  int idx = blockIdx.x*256 + threadIdx.x;   // over 8192*32 (one 16-ch group per thread)
  int m = idx >> 5, g = idx & 31;
  int b = m >> 10;
  float mean = stats[(b*32+g)*2];
  float rstd = stats[(b*32+g)*2+1];
  const float* xp = x + (size_t)m*CDIM + g*16;
  const float* sp = scale + g*16;
  const float* bp = bias + g*16;
  short8 o0, o1;
  #pragma unroll
  for (int j=0;j<16;++j){
    float v = (xp[j]-mean)*rstd*sp[j] + bp[j];
    if (j<8) o0[j] = (short)f2bf(v); else o1[j-8] = (short)f2bf(v);
  }
  short8* dst = (short8*)(xn + (size_t)m*CDIM + g*16);
  dst[0]=o0; dst[1]=o1;
}

// ---------------- GEMM: C = A(MxK) * Bt(NxK)^T, bf16 in, fp32 acc ----------------
#define BM 128
#define BN 128
#define BK 64

template<int EPI, int NT>
__global__ __launch_bounds__(256, 3) void gemm_bf16(
    const u16* __restrict__ A, const u16* __restrict__ Bt,
    const float* __restrict__ bias, const float* __restrict__ resid,
    float* __restrict__ outF,
    u16* __restrict__ qb, u16* __restrict__ kb, u16* __restrict__ vtb)
{
  const int K = CDIM;
  int t = threadIdx.x;
  int l = t & 63, wid = t >> 6;
  int g = l >> 4, c = l & 15;
  int wr = wid >> 1, wc = wid & 1;
  int nwg = gridDim.x;
  int cpx = nwg >> 3;
  int orig = blockIdx.x;
  int swz = (orig & 7)*cpx + (orig >> 3);
  int m0 = (swz / NT) * BM, n0 = (swz % NT) * BN;

  __shared__ __attribute__((aligned(16))) u16 ls[16384];   // 32 KB: lsA[0..8191], lsB[8192..]
  char* lsAc = (char*)ls; char* lsBc = (char*)(ls + 8192);

  f32x4 acc[4][4];
  #pragma unroll
  for (int i=0;i<4;++i)
    #pragma unroll
    for(int j=0;j<4;++j) acc[i][j] = (f32x4)0.f;

  int lrow = l >> 3, slot = l & 7;
  int scol = ((slot ^ lrow) << 3);
  const int KT = K / BK;  // 8
  for (int kt=0; kt<KT; ++kt){
    __syncthreads();
    int kbo = kt*BK;
    #pragma unroll
    for (int q2=0; q2<4; ++q2){
      int row = wid*32 + q2*8 + lrow;
      gld16(A  + (size_t)(m0+row)*K + kbo + scol, ls        + (wid*4+q2)*512);
      gld16(Bt + (size_t)(n0+row)*K + kbo + scol, ls + 8192 + (wid*4+q2)*512);
    }
    asm volatile("s_waitcnt vmcnt(0)" ::: "memory");
    __syncthreads();
    #pragma unroll
    for (int kk=0; kk<2; ++kk){
      short8 af[4], bfr[4];
      #pragma unroll
      for (int i=0;i<4;++i){
        int rowA = wr*64 + i*16 + c;
        af[i]  = *(const short8*)(lsAc + rowA*128 + ((kk*4+g) ^ (rowA&7))*16);
        int rowB = wc*64 + i*16 + c;
        bfr[i] = *(const short8*)(lsBc + rowB*128 + ((kk*4+g) ^ (rowB&7))*16);
      }
      #pragma unroll
      for (int i=0;i<4;++i)
        #pragma unroll
        for (int j=0;j<4;++j)
          acc[i][j] = __builtin_amdgcn_mfma_f32_16x16x32_bf16(af[i], bfr[j], acc[i][j], 0,0,0);
    }
  }

  if (EPI == 0){
    int b = m0 >> 10, s0 = m0 & (SLEN-1);
    __syncthreads();
    u16* lsC = ls;
    #pragma unroll
    for (int i=0;i<4;++i){
      int rl0 = wr*64 + i*16 + g*4;
      #pragma unroll
      for (int j=0;j<4;++j){
        int cl = wc*64 + j*16 + c;
        int gcol = n0 + cl;
        int jj = gcol % 192;
        float sc_ = (jj < 128) ? QK_SCALE : 1.0f;
        float bv = bias[gcol];
        #pragma unroll
        for (int r=0;r<4;++r)
          lsC[(rl0+r)*128 + cl] = f2bf((acc[i][j][r] + bv)*sc_);
      }
    }
    __syncthreads();
    #pragma unroll
    for (int cc=0; cc<8; ++cc){
      int ch = cc*256 + t;
      int rl = ch >> 4, slot2 = ch & 15;
      int cl = slot2*8;
      int gcol = n0 + cl;
      int h = gcol / 192, jj = gcol % 192;
      int s = s0 + rl;
      u32x4 vv = *(const u32x4*)(lsC + rl*128 + cl);
      size_t rowb = ((size_t)(b*NHEADS+h))*SLEN + s;
      if (jj < 64)       __builtin_nontemporal_store(vv, (u32x4*)(qb + rowb*HDIM + jj));
      else if (jj < 128) __builtin_nontemporal_store(vv, (u32x4*)(kb + rowb*HDIM + (jj-64)));
    }
    int blk3 = (n0 >> 7) % 3;
    if (blk3 != 0){
      __syncthreads();
      u16* lsV = ls;            // [64][136] padded
      #pragma unroll
      for (int i=0;i<4;++i){
        int rl0 = wr*64 + i*16 + g*4;
        #pragma unroll
        for (int j=0;j<4;++j){
          int cl = wc*64 + j*16 + c;
          int jj = (n0 + cl) % 192;
          if (jj >= 128){
            #pragma unroll
            for (int r=0;r<4;++r)
              lsV[(jj-128)*136 + rl0 + r] = f2bf(acc[i][j][r] + bias[n0+cl]);
          }
        }
      }
      __syncthreads();
      int hv = (n0 + ((blk3==1)?0:64)) / 192;
      size_t vbase = ((size_t)(b*NHEADS+hv))*HDIM*SLEN;
      #pragma unroll
      for (int cc=0; cc<4; ++cc){
        int chunk = cc*256 + t;
        int d = chunk >> 4, so = (chunk & 15)*8;
        u32x4 vv = *(const u32x4*)(lsV + d*136 + so);
        __builtin_nontemporal_store(vv, (u32x4*)(vtb + vbase + (size_t)d*SLEN + s0 + so));
      }
    }
  } else {
    #pragma unroll
    for (int i=0;i<4;++i){
      int grow = m0 + wr*64 + i*16 + g*4;
      #pragma unroll
      for (int j=0;j<4;++j){
        int gcol = n0 + wc*64 + j*16 + c;
        float bv = bias[gcol];
        #pragma unroll
        for (int r=0;r<4;++r){
          size_t off = (size_t)(grow+r)*CDIM + gcol;
          float rv = __builtin_nontemporal_load(&resid[off]);
          __builtin_nontemporal_store(acc[i][j][r] + bv + rv, &outF[off]);
        }
      }
    }
  }
}

// ---------------- fused flash attention: swapped-QK^T 32x32, PAIR-MERGED kv loop ----
// grid: 512 blocks (XCD-swizzled); block: 256 thr = 4 waves, each owns 32 q-rows.
// 2 kv-tiles per iteration: 4 independent QK chains + merged softmax over 64 vals.
// K/V staged via global_load_lds, 4 tile-buffers (pairs 0,1 prologue; pair p+2
// staged after post-compute barrier); counted vmcnt(8). permlane32_swap pack.
#define PV_KS(PT, QOFF, V0, V1, KS) { \
    u32 A0 = pk2(PT[QOFF+0], PT[QOFF+1]); \
    u32 A1 = pk2(PT[QOFF+2], PT[QOFF+3]); \
    u32 B0 = pk2(PT[QOFF+4], PT[QOFF+5]); \
    u32 B1 = pk2(PT[QOFF+6], PT[QOFF+7]); \
    auto r0_ = __builtin_amdgcn_permlane32_swap((int)A0, (int)B0, false, false); \
    auto r1_ = __builtin_amdgcn_permlane32_swap((int)A1, (int)B1, false, false); \
    uint4 w; \
    w.x = (u32)r0_[0]; w.y = (u32)r1_[0]; w.z = (u32)r0_[1]; w.w = (u32)r1_[1]; \
    short8 fP; __builtin_memcpy(&fP, &w, 16); \
    o0 = __builtin_amdgcn_mfma_f32_32x32x16_bf16(V0[KS], fP, o0, 0,0,0); \
    o1 = __builtin_amdgcn_mfma_f32_32x32x16_bf16(V1[KS], fP, o1, 0,0,0); }

__global__ __launch_bounds__(256, 2) void attn_fused(const u16* __restrict__ qg,
  const u16* __restrict__ kg, const u16* __restrict__ vtg, u16* __restrict__ og)
{
  int bid = blockIdx.x;
  int nid = (bid & 7)*64 + (bid >> 3);   // XCD-contiguous bh
  int bh = nid >> 3, qi = nid & 7;
  int t = threadIdx.x, l = t & 63, wid = t >> 6;
  int q = l & 31, hi = l >> 5;
  int q0 = qi*128 + wid*32;

  // 4 tile-buffers K and V: [4][64][64] bf16 = 32KB + 32KB
  __shared__ __attribute__((aligned(16))) u16 kl[4][4096];
  __shared__ __attribute__((aligned(16))) u16 vl[4][4096];

  const u16* qrow = qg + ((size_t)bh*SLEN + q0 + q)*HDIM + hi*8;
  short8 fQ[4];
  #pragma unroll
  for (int ds=0; ds<4; ++ds) fQ[ds] = *(const short8*)(qrow + ds*16);

  f32x16 o0, o1;
  #pragma unroll
  for (int r=0;r<16;++r){ o0[r]=0.f; o1[r]=0.f; }
  float mr = -1e30f, lsum = 0.f;

  const u16* kt_base = kg  + (size_t)bh*SLEN*HDIM;
  const u16* vt_base = vtg + (size_t)bh*HDIM*SLEN;
  int srow = l >> 3, sslot = l & 7;
  int scol8 = ((sslot ^ srow) << 3);   // pre-swizzled source column

#define STAGE(BUF, KV) { \
    _Pragma("unroll") \
    for (int j=0;j<2;++j){ \
      int row = wid*16 + j*8 + srow; \
      int chunk = wid*2 + j; \
      gld16(kt_base + (size_t)((KV)*64 + row)*HDIM + scol8, &kl[BUF][chunk*512]); \
      gld16(vt_base + (size_t)row*SLEN + (KV)*64 + scol8,   &vl[BUF][chunk*512]); \
    } }

  STAGE(0, 0)
  STAGE(1, 1)
  STAGE(2, 2)
  STAGE(3, 3)

  int sl_q = q & 7;
  for (int p=0; p<8; ++p){
    if (p < 7) asm volatile("s_waitcnt vmcnt(8)" ::: "memory");
    else       asm volatile("s_waitcnt vmcnt(0)" ::: "memory");
    __syncthreads();                    // pair p visible to all waves
    int tA = 2*p, tB = 2*p+1;
    const u16* kA = &kl[tA&3][0]; const u16* kB = &kl[tB&3][0];
    const u16* vA = &vl[tA&3][0]; const u16* vB = &vl[tB&3][0];
    // K fragments, both tiles (16 ds_read_b128)
    short8 fKA0[4], fKA1[4], fKB0[4], fKB1[4];
    #pragma unroll
    for (int ds=0; ds<4; ++ds){
      int sl = ((ds*2+hi) ^ sl_q) << 3;
      fKA0[ds] = *(const short8*)(kA + q*64 + sl);
      fKA1[ds] = *(const short8*)(kA + (q+32)*64 + sl);
      fKB0[ds] = *(const short8*)(kB + q*64 + sl);
      fKB1[ds] = *(const short8*)(kB + (q+32)*64 + sl);
    }
    f32x16 pA0, pA1, pB0, pB1;
    #pragma unroll
    for (int r=0;r<16;++r){ pA0[r]=0.f; pA1[r]=0.f; pB0[r]=0.f; pB1[r]=0.f; }
    __builtin_amdgcn_s_setprio(1);
    #pragma unroll
    for (int ds=0; ds<4; ++ds){        // 4 independent accumulation chains
      pA0 = __builtin_amdgcn_mfma_f32_32x32x16_bf16(fKA0[ds], fQ[ds], pA0, 0,0,0);
      pB0 = __builtin_amdgcn_mfma_f32_32x32x16_bf16(fKB0[ds], fQ[ds], pB0, 0,0,0);
      pA1 = __builtin_amdgcn_mfma_f32_32x32x16_bf16(fKA1[ds], fQ[ds], pA1, 0,0,0);
      pB1 = __builtin_amdgcn_mfma_f32_32x32x16_bf16(fKB1[ds], fQ[ds], pB1, 0,0,0);
    }
    __builtin_amdgcn_s_setprio(0);
    // V fragments, both tiles (issue early; latency hides under softmax)
    short8 fVA0[4], fVA1[4], fVB0[4], fVB1[4];
    #pragma unroll
    for (int ks=0; ks<4; ++ks){
      int sl = ((ks*2+hi) ^ sl_q) << 3;
      fVA0[ks] = *(const short8*)(vA + q*64 + sl);
      fVA1[ks] = *(const short8*)(vA + (q+32)*64 + sl);
      fVB0[ks] = *(const short8*)(vB + q*64 + sl);
      fVB1[ks] = *(const short8*)(vB + (q+32)*64 + sl);
    }
    // ---- merged online softmax over 64 vals, defer-max THR=8 ----
    float a8[8];
    #pragma unroll
    for (int r=0;r<8;++r){
      float ma = fmaxf(fmaxf(pA0[r],pA0[r+8]), fmaxf(pA1[r],pA1[r+8]));
      float mb = fmaxf(fmaxf(pB0[r],pB0[r+8]), fmaxf(pB1[r],pB1[r+8]));
      a8[r] = fmaxf(ma, mb);
    }
    #pragma unroll
    for (int s=4;s>0;s>>=1)
      #pragma unroll
      for (int r=0;r<4;++r) if (r<s) a8[r] = fmaxf(a8[r], a8[r+s]);
    auto rm_ = __builtin_amdgcn_permlane32_swap(
        __builtin_bit_cast(int, a8[0]), __builtin_bit_cast(int, a8[0]), false, false);
    float tmax = fmaxf(a8[0], fmaxf(__builtin_bit_cast(float, rm_[0]),
                                    __builtin_bit_cast(float, rm_[1])));
    if (!__all(tmax <= mr + 8.0f)){
      float mn = fmaxf(mr, tmax);
      float alpha = __expf(mr - mn);
      mr = mn;
      lsum *= alpha;
      #pragma unroll
      for (int r=0;r<16;++r){ o0[r]*=alpha; o1[r]*=alpha; }
    }
    #pragma unroll
    for (int r=0;r<16;++r){
      pA0[r] = __expf(pA0[r]-mr); pA1[r] = __expf(pA1[r]-mr);
      pB0[r] = __expf(pB0[r]-mr); pB1[r] = __expf(pB1[r]-mr);
    }
    float s8[8];
    #pragma unroll
    for (int r=0;r<8;++r)
      s8[r] = ((pA0[r]+pA0[r+8]) + (pA1[r]+pA1[r+8]))
            + ((pB0[r]+pB0[r+8]) + (pB1[r]+pB1[r+8]));
    #pragma unroll
    for (int s=4;s>0;s>>=1)
      #pragma unroll
      for (int r=0;r<4;++r) if (r<s) s8[r] += s8[r+s];
    auto rs_ = __builtin_amdgcn_permlane32_swap(
        __builtin_bit_cast(int, s8[0]), __builtin_bit_cast(int, s8[0]), false, false);
    lsum += __builtin_bit_cast(float, rs_[0]) + __builtin_bit_cast(float, rs_[1]);
    // ---- pack + PV, both tiles ----
    __builtin_amdgcn_s_setprio(1);
    PV_KS(pA0, 0, fVA0, fVA1, 0)
    PV_KS(pA0, 8, fVA0, fVA1, 1)
    PV_KS(pA1, 0, fVA0, fVA1, 2)
    PV_KS(pA1, 8, fVA0, fVA1, 3)
    PV_KS(pB0, 0, fVB0, fVB1, 0)
    PV_KS(pB0, 8, fVB0, fVB1, 1)
    PV_KS(pB1, 0, fVB0, fVB1, 2)
    PV_KS(pB1, 8, fVB0, fVB1, 3)
    __builtin_amdgcn_s_setprio(0);
    __syncthreads();                    // all waves done reading pair p
    if (p < 6){
      STAGE((2*p+4)&3, 2*p+4)           // overwrite pair p's buffers
      STAGE((2*p+5)&3, 2*p+5)
    }
  }

  // epilogue: O^T[d, q] -> og[b, s=q0+q, h*64 + d], d = (reg&3)+8*(reg>>2)+4*hi
  float inv = 1.f / lsum;
  int b = bh >> 3, h = bh & 7;
  u16* obase = og + ((size_t)b*SLEN + q0 + q)*CDIM + h*HDIM;
  #pragma unroll
  for (int pr=0; pr<8; ++pr){
    int d = ((2*pr)&3) + 8*(pr>>1) + 4*hi;
    *(u32*)(obase + d)      = pk2(o0[2*pr]*inv, o0[2*pr+1]*inv);
    *(u32*)(obase + 32 + d) = pk2(o1[2*pr]*inv, o1[2*pr+1]*inv);
  }
}

extern "C" void kernel_launch(void* const* d_in, const int* in_sizes, int n_in,
                              void* d_out, int out_size, void* d_ws, size_t ws_size,
                              hipStream_t stream){
  const float* x      = (const float*)d_in[0];
  const float* nscale = (const float*)d_in[1];
  const float* nbias  = (const float*)d_in[2];
  const float* wqkv   = (const float*)d_in[3];
  const float* bqkv   = (const float*)d_in[4];
  const float* wout   = (const float*)d_in[5];
  const float* bout   = (const float*)d_in[6];
  float* out = (float*)d_out;

  char* ws = (char*)d_ws;
  size_t off = 0;
  auto alloc = [&](size_t bytes){ void* p = ws + off; off += (bytes + 255) & ~255ull; return p; };
  float* stats  = (float*)alloc(256*2*sizeof(float));
  u16* wqkv_t = (u16*)alloc((size_t)NQKV*CDIM*2);
  u16* wout_t = (u16*)alloc((size_t)CDIM*CDIM*2);
  u16* xn     = (u16*)alloc((size_t)MROWS*CDIM*2);
  u16* qb     = (u16*)alloc((size_t)MROWS*CDIM*2);
  u16* kb     = (u16*)alloc((size_t)MROWS*CDIM*2);
  u16* vtb    = (u16*)alloc((size_t)MROWS*CDIM*2);
  u16* ob     = (u16*)alloc((size_t)MROWS*CDIM*2);

  prep_w<NQKV><<<dim3(8*(NQKV/64)), dim3(256), 0, stream>>>(wqkv, wqkv_t);
  prep_w<CDIM><<<dim3(8*(CDIM/64)), dim3(256), 0, stream>>>(wout, wout_t);
  gn_stats <<<dim3(256), dim3(256), 0, stream>>>(x, stats);
  norm_cast<<<dim3((MROWS*32)/256), dim3(256), 0, stream>>>(x, stats, nscale, nbias, xn);
  gemm_bf16<0,12><<<dim3(768), dim3(256), 0, stream>>>(xn, wqkv_t, bqkv, nullptr, nullptr, qb, kb, vtb);
  attn_fused<<<dim3(512), dim3(256), 0, stream>>>(qb, kb, vtb, ob);
  gemm_bf16<1,4><<<dim3(256), dim3(256), 0, stream>>>(ob, wout_t, bout, x, out, nullptr, nullptr, nullptr);
}